// Round 1
// baseline (3068.232 us; speedup 1.0000x reference)
//
#include <hip/hip_runtime.h>
#include <hip/hip_bf16.h>

#define B_N 2048
#define D_N 4096
#define H_N 1024
#define L_N 64

typedef __attribute__((ext_vector_type(8))) short short8;
typedef __attribute__((ext_vector_type(4))) float float4_t;

#define ASG __attribute__((address_space(1)))
#define ASL __attribute__((address_space(3)))

__device__ inline float bf2f(unsigned short u) {
  union { unsigned u; float f; } v; v.u = ((unsigned)u) << 16; return v.f;
}
__device__ inline unsigned short f2bf(float f) {
  union { float f; unsigned u; } v; v.f = f;
  unsigned r = v.u + 0x7fffu + ((v.u >> 16) & 1u);
  return (unsigned short)(r >> 16);
}

__device__ inline float block_sum256(float v) {
  const int lane = threadIdx.x & 63, wave = threadIdx.x >> 6;
#pragma unroll
  for (int off = 32; off; off >>= 1) v += __shfl_xor(v, off);
  __shared__ float red_s[4];
  if (lane == 0) red_s[wave] = v;
  __syncthreads();
  return red_s[0] + red_s[1] + red_s[2] + red_s[3];
}

__device__ inline float block_max256(float v) {
  const int lane = threadIdx.x & 63, wave = threadIdx.x >> 6;
#pragma unroll
  for (int off = 32; off; off >>= 1) v = fmaxf(v, __shfl_xor(v, off));
  __shared__ float redm_s[4];
  if (lane == 0) redm_s[wave] = v;
  __syncthreads();
  return fmaxf(fmaxf(redm_s[0], redm_s[1]), fmaxf(redm_s[2], redm_s[3]));
}

// ---------------- prep kernels ----------------

// cast x row to bf16 + row sum of squares (fp32)
__global__ __launch_bounds__(256) void prep_x(const float* __restrict__ x,
                                              unsigned short* __restrict__ xb,
                                              float* __restrict__ sqx) {
  const int row = blockIdx.x;
  const int t = threadIdx.x;
  const float4* xr = (const float4*)(x + (size_t)row * D_N);
  ushort4* xbr = (ushort4*)(xb + (size_t)row * D_N);
  float s = 0.f;
  for (int i = t; i < D_N / 4; i += 256) {
    float4 v = xr[i];
    s += v.x * v.x + v.y * v.y + v.z * v.z + v.w * v.w;
    ushort4 o;
    o.x = f2bf(v.x); o.y = f2bf(v.y); o.z = f2bf(v.z); o.w = f2bf(v.w);
    xbr[i] = o;
  }
  float tot = block_sum256(s);
  if (t == 0) sqx[row] = tot;
}

// transpose-cast: in (R x C) fp32 -> out (C x R) bf16
__global__ __launch_bounds__(256) void transpose_cast(const float* __restrict__ in,
                                                      unsigned short* __restrict__ out,
                                                      int R, int C) {
  __shared__ float tile[32][33];
  const int c0 = blockIdx.x * 32, r0 = blockIdx.y * 32;
  const int tx = threadIdx.x, ty = threadIdx.y;
#pragma unroll
  for (int i = 0; i < 32; i += 8)
    tile[ty + i][tx] = in[(size_t)(r0 + ty + i) * C + c0 + tx];
  __syncthreads();
#pragma unroll
  for (int i = 0; i < 32; i += 8)
    out[(size_t)(c0 + ty + i) * R + r0 + tx] = f2bf(tile[tx][ty + i]);
}

__global__ void init_accum(float* accum) {
  if (threadIdx.x < 2) accum[threadIdx.x] = 0.f;  // [0]=rec_sum, [1]=max bits (0u == 0.0f)
}

// ---------------- MFMA GEMM (128x128 tile, BK=32, 256 threads) ----------------
// A: M x K bf16 row-major.  Bt: N x K bf16 row-major (i.e. B transposed).
// C = A @ B.  Frag layouts per cdna4 guide (m89/m91 verified).

__device__ inline void gemm_mainloop(const unsigned short* __restrict__ A,
                                     const unsigned short* __restrict__ Bt,
                                     int K, int m_base, int n_base,
                                     float4_t acc[4][4]) {
  __shared__ unsigned short lA[128 * 32];
  __shared__ unsigned short lB[128 * 32];
  const int t = threadIdx.x;
  const int wave = t >> 6;
  const int lane = t & 63;
  const int lrow = lane & 15;
  const int quad = lane >> 4;
  const int wm = (wave & 1) * 64;
  const int wn = (wave >> 1) * 64;

  const int srow = lane >> 2;        // 0..15 within chunk
  const int scol = (lane & 3) * 8;   // k offset (ushorts)

  for (int k0 = 0; k0 < K; k0 += 32) {
    __syncthreads();  // protect LDS from overwrite while previous iter still reading
#pragma unroll
    for (int q = 0; q < 2; ++q) {
      const int rbase = wave * 32 + q * 16;
      const int row = rbase + srow;
      __builtin_amdgcn_global_load_lds(
          (ASG void*)(A + (size_t)(m_base + row) * K + k0 + scol),
          (ASL void*)(lA + rbase * 32), 16, 0, 0);
      __builtin_amdgcn_global_load_lds(
          (ASG void*)(Bt + (size_t)(n_base + row) * K + k0 + scol),
          (ASL void*)(lB + rbase * 32), 16, 0, 0);
    }
    __syncthreads();  // compiler emits vmcnt(0) before barrier -> data ready
    short8 af[4], bfr[4];
#pragma unroll
    for (int f = 0; f < 4; ++f) {
      af[f]  = *(const short8*)(lA + (wm + f * 16 + lrow) * 32 + quad * 8);
      bfr[f] = *(const short8*)(lB + (wn + f * 16 + lrow) * 32 + quad * 8);
    }
#pragma unroll
    for (int fm = 0; fm < 4; ++fm)
#pragma unroll
      for (int fn = 0; fn < 4; ++fn)
        acc[fm][fn] = __builtin_amdgcn_mfma_f32_16x16x32_bf16(af[fm], bfr[fn],
                                                              acc[fm][fn], 0, 0, 0);
  }
}

// epilogue 0: Out = bf16(relu(C + bias))
__global__ __launch_bounds__(256) void gemm_bias_relu(const unsigned short* __restrict__ A,
                                                      const unsigned short* __restrict__ Bt,
                                                      const float* __restrict__ bias,
                                                      unsigned short* __restrict__ Out,
                                                      int K, int N) {
  float4_t acc[4][4];
  float4_t z4 = {0.f, 0.f, 0.f, 0.f};
#pragma unroll
  for (int a = 0; a < 4; ++a)
#pragma unroll
    for (int b = 0; b < 4; ++b) acc[a][b] = z4;
  const int m_base = blockIdx.y * 128, n_base = blockIdx.x * 128;
  gemm_mainloop(A, Bt, K, m_base, n_base, acc);
  const int t = threadIdx.x, wave = t >> 6, lane = t & 63;
  const int lrow = lane & 15, quad = lane >> 4;
  const int wm = (wave & 1) * 64, wn = (wave >> 1) * 64;
#pragma unroll
  for (int fm = 0; fm < 4; ++fm)
#pragma unroll
    for (int fn = 0; fn < 4; ++fn) {
      const int r0 = m_base + wm + fm * 16 + quad * 4;
      const int c = n_base + wn + fn * 16 + lrow;
      const float bc = bias[c];
#pragma unroll
      for (int r = 0; r < 4; ++r)
        Out[(size_t)(r0 + r) * N + c] = f2bf(fmaxf(acc[fm][fn][r] + bc, 0.f));
    }
}

// epilogue 1: accumulate sum((C + bias - Xref)^2) -> atomicAdd(acc_slot)
__global__ __launch_bounds__(256) void gemm_recloss(const unsigned short* __restrict__ A,
                                                    const unsigned short* __restrict__ Bt,
                                                    const float* __restrict__ bias,
                                                    const float* __restrict__ Xref,
                                                    float* __restrict__ acc_slot,
                                                    int K, int N) {
  float4_t acc[4][4];
  float4_t z4 = {0.f, 0.f, 0.f, 0.f};
#pragma unroll
  for (int a = 0; a < 4; ++a)
#pragma unroll
    for (int b = 0; b < 4; ++b) acc[a][b] = z4;
  const int m_base = blockIdx.y * 128, n_base = blockIdx.x * 128;
  gemm_mainloop(A, Bt, K, m_base, n_base, acc);
  const int t = threadIdx.x, wave = t >> 6, lane = t & 63;
  const int lrow = lane & 15, quad = lane >> 4;
  const int wm = (wave & 1) * 64, wn = (wave >> 1) * 64;
  float local = 0.f;
#pragma unroll
  for (int fm = 0; fm < 4; ++fm)
#pragma unroll
    for (int fn = 0; fn < 4; ++fn) {
      const int r0 = m_base + wm + fm * 16 + quad * 4;
      const int c = n_base + wn + fn * 16 + lrow;
      const float bc = bias[c];
#pragma unroll
      for (int r = 0; r < 4; ++r) {
        float v = acc[fm][fn][r] + bc - Xref[(size_t)(r0 + r) * N + c];
        local += v * v;
      }
    }
  float tot = block_sum256(local);
  if (t == 0) atomicAdd(acc_slot, tot);
}

// epilogue 2: d2 = max(sq[row]+sq[col]-2C, 0); store fp32; track global max (uint monotone)
__global__ __launch_bounds__(256) void gemm_d2(const unsigned short* __restrict__ A,
                                               const unsigned short* __restrict__ Bt,
                                               const float* __restrict__ sq,
                                               float* __restrict__ Out,
                                               unsigned* __restrict__ max_slot,
                                               int K, int N) {
  float4_t acc[4][4];
  float4_t z4 = {0.f, 0.f, 0.f, 0.f};
#pragma unroll
  for (int a = 0; a < 4; ++a)
#pragma unroll
    for (int b = 0; b < 4; ++b) acc[a][b] = z4;
  const int m_base = blockIdx.y * 128, n_base = blockIdx.x * 128;
  gemm_mainloop(A, Bt, K, m_base, n_base, acc);
  const int t = threadIdx.x, wave = t >> 6, lane = t & 63;
  const int lrow = lane & 15, quad = lane >> 4;
  const int wm = (wave & 1) * 64, wn = (wave >> 1) * 64;
  float lmax = 0.f;
#pragma unroll
  for (int fm = 0; fm < 4; ++fm)
#pragma unroll
    for (int fn = 0; fn < 4; ++fn) {
      const int r0 = m_base + wm + fm * 16 + quad * 4;
      const int c = n_base + wn + fn * 16 + lrow;
      const float sqc = sq[c];
#pragma unroll
      for (int r = 0; r < 4; ++r) {
        float v = fmaxf(sq[r0 + r] + sqc - 2.f * acc[fm][fn][r], 0.f);
        Out[(size_t)(r0 + r) * N + c] = v;
        lmax = fmaxf(lmax, v);
      }
    }
  float tot = block_max256(lmax);
  if (t == 0) atomicMax(max_slot, __float_as_uint(tot));
}

// ---------------- small vector kernels ----------------

// z = h1(bf16) @ W2 + b2   (M=2048, K=1024, N=64); block = 4 rows x 64 cols
__global__ __launch_bounds__(256) void g2_k(const unsigned short* __restrict__ h1b,
                                            const float* __restrict__ W2,
                                            const float* __restrict__ b2,
                                            float* __restrict__ z) {
  const int col = threadIdx.x & 63;
  const int row = blockIdx.x * 4 + (threadIdx.x >> 6);
  const unsigned short* hr = h1b + (size_t)row * H_N;
  float a0 = 0.f, a1 = 0.f, a2 = 0.f, a3 = 0.f;
  for (int k = 0; k < H_N; k += 4) {
    a0 += bf2f(hr[k + 0]) * W2[(k + 0) * L_N + col];
    a1 += bf2f(hr[k + 1]) * W2[(k + 1) * L_N + col];
    a2 += bf2f(hr[k + 2]) * W2[(k + 2) * L_N + col];
    a3 += bf2f(hr[k + 3]) * W2[(k + 3) * L_N + col];
  }
  z[(size_t)row * L_N + col] = (a0 + a1) + (a2 + a3) + b2[col];
}

// sqz: row sums of squares of z; one wave per row
__global__ __launch_bounds__(256) void sqz_k(const float* __restrict__ z,
                                             float* __restrict__ sqz) {
  const int lane = threadIdx.x & 63;
  const int row = blockIdx.x * 4 + (threadIdx.x >> 6);
  float v = z[(size_t)row * L_N + lane];
  float s = v * v;
#pragma unroll
  for (int off = 32; off; off >>= 1) s += __shfl_xor(s, off);
  if (lane == 0) sqz[row] = s;
}

// h2 = bf16(relu(z @ W3 + b3))   (M=2048, K=64, N=1024); 4 rows per block
__global__ __launch_bounds__(256) void g3_k(const float* __restrict__ z,
                                            const float* __restrict__ W3,
                                            const float* __restrict__ b3,
                                            unsigned short* __restrict__ h2b) {
  const int t = threadIdx.x;
  const int col = blockIdx.y * 256 + t;
  const int r0 = blockIdx.x * 4;
  __shared__ float zr[4][64];
  zr[t >> 6][t & 63] = z[(size_t)(r0 + (t >> 6)) * L_N + (t & 63)];
  __syncthreads();
  const float bc = b3[col];
  float a0 = bc, a1 = bc, a2 = bc, a3 = bc;
#pragma unroll 8
  for (int k = 0; k < 64; ++k) {
    float w = W3[k * H_N + col];
    a0 += zr[0][k] * w;
    a1 += zr[1][k] * w;
    a2 += zr[2][k] * w;
    a3 += zr[3][k] * w;
  }
  h2b[(size_t)(r0 + 0) * H_N + col] = f2bf(fmaxf(a0, 0.f));
  h2b[(size_t)(r0 + 1) * H_N + col] = f2bf(fmaxf(a1, 0.f));
  h2b[(size_t)(r0 + 2) * H_N + col] = f2bf(fmaxf(a2, 0.f));
  h2b[(size_t)(r0 + 3) * H_N + col] = f2bf(fmaxf(a3, 0.f));
}

// d2z: full 2048x2048 squared distances of z (fp32, K=64); 16x16 tile per block
__global__ __launch_bounds__(256) void d2z_k(const float* __restrict__ z,
                                             const float* __restrict__ sqz,
                                             float* __restrict__ d2z) {
  const int bi = blockIdx.y * 16, bj = blockIdx.x * 16;
  __shared__ float zi[16][65], zj[16][65];
  const int t = threadIdx.x;
  for (int idx = t; idx < 16 * 64; idx += 256) {
    const int r = idx >> 6, c = idx & 63;
    zi[r][c] = z[(size_t)(bi + r) * L_N + c];
    zj[r][c] = z[(size_t)(bj + r) * L_N + c];
  }
  __syncthreads();
  const int ti = t >> 4, tj = t & 15;
  float dot = 0.f;
#pragma unroll 8
  for (int k = 0; k < 64; ++k) dot += zi[ti][k] * zj[tj][k];
  float v = fmaxf(sqz[bi + ti] + sqz[bj + tj] - 2.f * dot, 0.f);
  d2z[(size_t)(bi + ti) * B_N + bj + tj] = v;
}

// ---------------- MST (Prim, exact semantics on d^2 — monotone w/ sqrt) ----------------
// block 0: d2x tree; block 1: d2z tree. 1024 threads, each owns nodes t and t+1024.
__global__ __launch_bounds__(1024) void mst_k(const float* __restrict__ d2x,
                                              const float* __restrict__ d2z,
                                              int2* __restrict__ edges) {
  const float* d2 = blockIdx.x ? d2z : d2x;
  int2* eo = edges + (size_t)blockIdx.x * (B_N - 1);
  const int t = threadIdx.x;
  const int lane = t & 63, wave = t >> 6;
  const int j0 = t, j1 = t + 1024;
  float md0 = d2[j0], md1 = d2[j1];
  int p0 = 0, p1 = 0;
  bool it0 = (j0 == 0), it1 = false;
  __shared__ unsigned long long wmin[16];
  __shared__ int bjs;
  for (int step = 0; step < B_N - 1; ++step) {
    unsigned long long c0 =
        it0 ? ~0ull : ((((unsigned long long)__float_as_uint(md0)) << 32) | (unsigned)j0);
    unsigned long long c1 =
        it1 ? ~0ull : ((((unsigned long long)__float_as_uint(md1)) << 32) | (unsigned)j1);
    unsigned long long c = c0 < c1 ? c0 : c1;
#pragma unroll
    for (int off = 32; off; off >>= 1) {
      unsigned long long o = __shfl_xor(c, off);
      if (o < c) c = o;
    }
    if (lane == 0) wmin[wave] = c;
    __syncthreads();
    if (t < 64) {
      unsigned long long v = (t < 16) ? wmin[t] : ~0ull;
#pragma unroll
      for (int off = 8; off; off >>= 1) {
        unsigned long long o = __shfl_xor(v, off);
        if (o < v) v = o;
      }
      if (t == 0) bjs = (int)(unsigned)(v & 0xffffffffull);
    }
    __syncthreads();
    const int j = bjs;
    if (j == j0) { eo[step] = make_int2(p0, j0); it0 = true; }
    if (j == j1) { eo[step] = make_int2(p1, j1); it1 = true; }
    const float* rowp = d2 + (size_t)j * B_N;
    float r0v = rowp[j0], r1v = rowp[j1];
    if (!it0 && r0v < md0) { md0 = r0v; p0 = j; }
    if (!it1 && r1v < md1) { md1 = r1v; p1 = j; }
  }
}

// ---------------- final: signature sums + rec loss ----------------
__global__ __launch_bounds__(256) void final_k(const float* __restrict__ d2x,
                                               const float* __restrict__ d2z,
                                               const int2* __restrict__ edges,
                                               const float* __restrict__ accum,
                                               const float* __restrict__ latent_norm,
                                               float* __restrict__ out) {
  const int t = threadIdx.x;
  const float maxd = sqrtf(__uint_as_float(((const unsigned*)accum)[1]));
  const float inv_maxd = 1.0f / maxd;
  const float inv_ln = 1.0f / latent_norm[0];
  float local = 0.f;
  for (int e = t; e < 2 * (B_N - 1); e += 256) {
    int2 ij = edges[e];
    size_t idx = (size_t)ij.x * B_N + ij.y;
    float xd = sqrtf(d2x[idx]) * inv_maxd;
    float zd = sqrtf(d2z[idx]) * inv_ln;
    float d = xd - zd;
    local += d * d;
  }
  float topo = block_sum256(local);
  if (t == 0)
    out[0] = accum[0] * (1.0f / ((float)B_N * (float)D_N)) + topo * (1.0f / (float)B_N);
}

// ---------------- launcher ----------------
extern "C" void kernel_launch(void* const* d_in, const int* in_sizes, int n_in,
                              void* d_out, int out_size, void* d_ws, size_t ws_size,
                              hipStream_t stream) {
  const float* x  = (const float*)d_in[0];
  const float* W1 = (const float*)d_in[1];
  const float* b1 = (const float*)d_in[2];
  const float* W2 = (const float*)d_in[3];
  const float* b2 = (const float*)d_in[4];
  const float* W3 = (const float*)d_in[5];
  const float* b3 = (const float*)d_in[6];
  const float* W4 = (const float*)d_in[7];
  const float* b4 = (const float*)d_in[8];
  const float* latent_norm = (const float*)d_in[9];
  float* out = (float*)d_out;

  char* ws = (char*)d_ws;
  size_t off = 0;
  auto alloc = [&](size_t bytes) {
    size_t o = off;
    off += (bytes + 255) & ~(size_t)255;
    return o;
  };
  unsigned short* xb   = (unsigned short*)(ws + alloc((size_t)B_N * D_N * 2));
  unsigned short* w1bt = (unsigned short*)(ws + alloc((size_t)H_N * D_N * 2));
  unsigned short* w4bt = (unsigned short*)(ws + alloc((size_t)D_N * H_N * 2));
  unsigned short* h1b  = (unsigned short*)(ws + alloc((size_t)B_N * H_N * 2));
  unsigned short* h2b  = (unsigned short*)(ws + alloc((size_t)B_N * H_N * 2));
  float* z    = (float*)(ws + alloc((size_t)B_N * L_N * 4));
  float* sqx  = (float*)(ws + alloc((size_t)B_N * 4));
  float* sqz  = (float*)(ws + alloc((size_t)B_N * 4));
  float* d2x  = (float*)(ws + alloc((size_t)B_N * B_N * 4));
  float* d2z  = (float*)(ws + alloc((size_t)B_N * B_N * 4));
  int2* edges = (int2*)(ws + alloc((size_t)2 * (B_N - 1) * sizeof(int2)));
  float* accum = (float*)(ws + alloc(256));  // [0]=rec_sum, [1]=max d2x bits

  init_accum<<<1, 64, 0, stream>>>(accum);
  prep_x<<<B_N, 256, 0, stream>>>(x, xb, sqx);
  transpose_cast<<<dim3(H_N / 32, D_N / 32), dim3(32, 8), 0, stream>>>(W1, w1bt, D_N, H_N);
  transpose_cast<<<dim3(D_N / 32, H_N / 32), dim3(32, 8), 0, stream>>>(W4, w4bt, H_N, D_N);
  // h1 = relu(x@W1 + b1)
  gemm_bias_relu<<<dim3(H_N / 128, B_N / 128), 256, 0, stream>>>(xb, w1bt, b1, h1b, D_N, H_N);
  // z = h1@W2 + b2
  g2_k<<<B_N / 4, 256, 0, stream>>>(h1b, W2, b2, z);
  sqz_k<<<B_N / 4, 256, 0, stream>>>(z, sqz);
  // h2 = relu(z@W3 + b3)
  g3_k<<<dim3(B_N / 4, H_N / 256), 256, 0, stream>>>(z, W3, b3, h2b);
  // rec_sum += sum((h2@W4 + b4 - x)^2)
  gemm_recloss<<<dim3(D_N / 128, B_N / 128), 256, 0, stream>>>(h2b, w4bt, b4, x, accum, H_N, D_N);
  // d2x = cdist^2(x) via x@x^T; track max
  gemm_d2<<<dim3(B_N / 128, B_N / 128), 256, 0, stream>>>(xb, xb, sqx, d2x,
                                                          (unsigned*)(accum + 1), D_N, B_N);
  // d2z = cdist^2(z) fp32
  d2z_k<<<dim3(B_N / 16, B_N / 16), 256, 0, stream>>>(z, sqz, d2z);
  // both MSTs (Prim, exact) — 2 blocks
  mst_k<<<2, 1024, 0, stream>>>(d2x, d2z, edges);
  final_k<<<1, 256, 0, stream>>>(d2x, d2z, edges, accum, latent_norm, out);
}